// Round 6
// baseline (164.016 us; speedup 1.0000x reference)
//
#include <hip/hip_runtime.h>
#include <hip/hip_bf16.h>
#include <math.h>

#define N 4096
#define D 256
#define SCALEF 10.0f
#define EPSF 1e-5f
#define MARGIN_INTRA 40.0f
#define MARGIN_INTER 6.0f
// reference excludes sorted_intra[0:4] = diagonal + top-3 non-diag, sorted_inter[0:6]
#define LI 3
#define LX 6
#define NJB 32              // j-blocks of 128
#define NIB 32              // i-blocks of 128
#define PPARTS (NJB * 2)    // partials per row: (j-block, wr)

typedef unsigned short ushort_t;
typedef __attribute__((ext_vector_type(8))) short short8;
typedef __attribute__((ext_vector_type(4))) float floatx4;

__device__ __forceinline__ float fast_sqrtf(float x) {
    return __builtin_amdgcn_sqrtf(x);  // raw v_sqrt_f32 (NOT CUDA __sqrtf — no such HIP symbol)
}

__device__ __forceinline__ ushort_t f2bf(float x) {
    __hip_bfloat16 h = __float2bfloat16(x);
    return *reinterpret_cast<ushort_t*>(&h);
}
__device__ __forceinline__ float bf2f(ushort_t u) {
    __hip_bfloat16 h = *reinterpret_cast<__hip_bfloat16*>(&u);
    return __bfloat162float(h);
}

template <int L>
__device__ __forceinline__ void bubble_insert(float (&t)[L], float v) {
#pragma unroll
    for (int q = 0; q < L; ++q) {
        float hi = fmaxf(t[q], v);
        v = fminf(t[q], v);
        t[q] = hi;
    }
}

// ---------------- Kernel 0: stable counting sort of rows by camid ----------
// 8 waves, wave w handles camera w. Also zeroes out[0] for merge's atomics.
__global__ __launch_bounds__(512) void perm_kernel(const int* __restrict__ camid,
                                                   int* __restrict__ perm,
                                                   int* __restrict__ camid_s,
                                                   float* __restrict__ out) {
    __shared__ int counts[8];
    int wave = threadIdx.x >> 6, lane = threadIdx.x & 63;
    if (threadIdx.x == 0) out[0] = 0.0f;
    int cnt = 0;
#pragma unroll 1
    for (int c = 0; c < N / 64; ++c) {
        int v = camid[c * 64 + lane];
        unsigned long long m = __ballot(v == wave);
        cnt += __popcll(m);
    }
    if (lane == 0) counts[wave] = cnt;
    __syncthreads();
    int base = 0;
    for (int c = 0; c < wave; ++c) base += counts[c];
#pragma unroll 1
    for (int c = 0; c < N / 64; ++c) {
        int idx = c * 64 + lane;
        int v = camid[idx];
        unsigned long long m = __ballot(v == wave);
        if (v == wave) {
            int pre = __popcll(m & ((1ull << lane) - 1ull));
            perm[base + pre] = idx;
            camid_s[base + pre] = wave;
        }
        base += __popcll(m);
    }
}

// ---------------- Kernel 1: gather + sq + R + bf16 hi/lo split ----------------
__global__ __launch_bounds__(64) void prep_kernel(const float* __restrict__ F,
                                                  const int* __restrict__ perm,
                                                  ushort_t* __restrict__ Fhi,
                                                  ushort_t* __restrict__ Flo,
                                                  float* __restrict__ sq,
                                                  float* __restrict__ Rrow) {
    int row = blockIdx.x;
    int orig = perm[row];
    int lane = threadIdx.x;
    float4 v = ((const float4*)(F + (size_t)orig * D))[lane];
    ushort4 h, l;
    h.x = f2bf(v.x); l.x = f2bf(v.x - bf2f(h.x));
    h.y = f2bf(v.y); l.y = f2bf(v.y - bf2f(h.y));
    h.z = f2bf(v.z); l.z = f2bf(v.z - bf2f(h.z));
    h.w = f2bf(v.w); l.w = f2bf(v.w - bf2f(h.w));
    ((ushort4*)(Fhi + (size_t)row * D))[lane] = h;
    ((ushort4*)(Flo + (size_t)row * D))[lane] = l;
    float s = v.x * v.x + v.y * v.y + v.z * v.z + v.w * v.w;
#pragma unroll
    for (int off = 32; off > 0; off >>= 1) s += __shfl_down(s, off, 64);
    if (lane == 0) {
        sq[row] = s;
        Rrow[row] = -SCALEF * sqrtf(2.0f * s);  // per-row exp reference shift
    }
}

// ---------------- Kernel 2: fused GEMM + online masked-topk-LSE ----------------
// Block: 128 rows (i) x 128 cols (j), all in camera-sorted index space.
// Gram tile TRANSPOSED: MFMA A <- j-features, B <- i-features, so each lane's
// accumulator holds 4 rows (ni) x 16 j. Camera-disjoint tiles take a fast
// inter-only epilogue (block-uniform branch).
#define LDST 40  // padded LDS row stride (80 B)

__global__ __launch_bounds__(256, 3) void fused_kernel(
    const ushort_t* __restrict__ Fhi, const ushort_t* __restrict__ Flo,
    const float* __restrict__ sq, const float* __restrict__ Rrow,
    const int* __restrict__ camid_s,
    float4* __restrict__ partA, float4* __restrict__ partB, float4* __restrict__ partC) {
    __shared__ ushort_t lds[4][128 * LDST];  // Ajhi, Ajlo, Bihi, Bilo = 40960 B
    int tid = threadIdx.x;
    int wave = tid >> 6, lane = tid & 63;
    int wr = wave >> 1, wc = wave & 1;   // wr: j-half (64), wc: i-half (64)
    int lane15 = lane & 15, quad = lane >> 4;
    int cid = blockIdx.x, sid = blockIdx.y;
    int i0 = sid * 128, j0 = cid * 128;

    // block-uniform camera-range disjointness (camid_s is sorted)
    int ci_lo = camid_s[i0], ci_hi = camid_s[i0 + 127];
    int cj_lo = camid_s[j0], cj_hi = camid_s[j0 + 127];
    bool disjoint = (ci_hi < cj_lo) || (cj_hi < ci_lo);

    float si[4], Ri4[4];
    int ci4[4], ig[4];
#pragma unroll
    for (int ni = 0; ni < 4; ++ni) {
        int i = i0 + wc * 64 + ni * 16 + lane15;
        ig[ni] = i;
        si[ni] = sq[i];
        Ri4[ni] = Rrow[i];
        ci4[ni] = camid_s[i];
    }

    float tI[4][LI], tX[4][LX], sIa[4], sXa[4];
#pragma unroll
    for (int ni = 0; ni < 4; ++ni) {
#pragma unroll
        for (int q = 0; q < LI; ++q) tI[ni][q] = -INFINITY;
#pragma unroll
        for (int q = 0; q < LX; ++q) tX[ni][q] = -INFINITY;
        sIa[ni] = 0.0f; sXa[ni] = 0.0f;
    }

    int srow = tid >> 1, shalf = tid & 1;
    const ushort_t* gAh = Fhi + (size_t)(j0 + srow) * D + shalf * 16;
    const ushort_t* gAl = Flo + (size_t)(j0 + srow) * D + shalf * 16;
    const ushort_t* gBh = Fhi + (size_t)(i0 + srow) * D + shalf * 16;
    const ushort_t* gBl = Flo + (size_t)(i0 + srow) * D + shalf * 16;
    ushort_t* sdst = &lds[0][0] + srow * LDST + shalf * 16;

    floatx4 acc[4][4] = {};

#pragma unroll 1
    for (int kt = 0; kt < 8; ++kt) {
        int koff = kt * 32;
        short8 ra[2], rb[2], rc[2], rd[2];
#pragma unroll
        for (int q = 0; q < 2; ++q) {
            ra[q] = *(const short8*)(gAh + koff + q * 8);
            rb[q] = *(const short8*)(gAl + koff + q * 8);
            rc[q] = *(const short8*)(gBh + koff + q * 8);
            rd[q] = *(const short8*)(gBl + koff + q * 8);
        }
        __syncthreads();
#pragma unroll
        for (int q = 0; q < 2; ++q) {
            *(short8*)(sdst + 0 * 128 * LDST + q * 8) = ra[q];
            *(short8*)(sdst + 1 * 128 * LDST + q * 8) = rb[q];
            *(short8*)(sdst + 2 * 128 * LDST + q * 8) = rc[q];
            *(short8*)(sdst + 3 * 128 * LDST + q * 8) = rd[q];
        }
        __syncthreads();

        short8 ahi[4], alo[4], bhi[4], blo[4];
        int eoff = quad * 8;
#pragma unroll
        for (int mi = 0; mi < 4; ++mi) {
            int r = wr * 64 + mi * 16 + lane15;  // j-side rows
            ahi[mi] = *(const short8*)(&lds[0][0] + r * LDST + eoff);
            alo[mi] = *(const short8*)(&lds[1][0] + r * LDST + eoff);
        }
#pragma unroll
        for (int ni = 0; ni < 4; ++ni) {
            int r = wc * 64 + ni * 16 + lane15;  // i-side rows
            bhi[ni] = *(const short8*)(&lds[2][0] + r * LDST + eoff);
            blo[ni] = *(const short8*)(&lds[3][0] + r * LDST + eoff);
        }
#pragma unroll
        for (int mi = 0; mi < 4; ++mi)
#pragma unroll
            for (int ni = 0; ni < 4; ++ni) {
                acc[mi][ni] = __builtin_amdgcn_mfma_f32_16x16x32_bf16(ahi[mi], bhi[ni], acc[mi][ni], 0, 0, 0);
                acc[mi][ni] = __builtin_amdgcn_mfma_f32_16x16x32_bf16(ahi[mi], blo[ni], acc[mi][ni], 0, 0, 0);
                acc[mi][ni] = __builtin_amdgcn_mfma_f32_16x16x32_bf16(alo[mi], bhi[ni], acc[mi][ni], 0, 0, 0);
            }
    }

    // epilogue: acc[mi][ni][r] <-> (j = j0 + wr*64 + mi*16 + quad*4 + r, i = ig[ni])
    if (disjoint) {
        // pure inter: no intra path, no camid compare, no diagonal possible
#pragma unroll
        for (int mi = 0; mi < 4; ++mi) {
            int jg0 = j0 + wr * 64 + mi * 16 + quad * 4;
            float4 sj4 = *(const float4*)(sq + jg0);
            const float* sjp = (const float*)&sj4;
#pragma unroll
            for (int ni = 0; ni < 4; ++ni) {
                float sb = si[ni] + EPSF;
#pragma unroll
                for (int r = 0; r < 4; ++r) {
                    float d2 = fmaxf(fmaf(-2.0f, acc[mi][ni][r], sb + sjp[r]), 1e-12f);
                    float x = -SCALEF * fast_sqrtf(d2);
                    sXa[ni] += __expf(x - Ri4[ni]);
                    bubble_insert<LX>(tX[ni], x);
                }
            }
        }
    } else {
#pragma unroll
        for (int mi = 0; mi < 4; ++mi) {
            int jg0 = j0 + wr * 64 + mi * 16 + quad * 4;
            float4 sj4 = *(const float4*)(sq + jg0);
            int4 cj4 = *(const int4*)(camid_s + jg0);
            const float* sjp = (const float*)&sj4;
            const int* cjp = (const int*)&cj4;
#pragma unroll
            for (int ni = 0; ni < 4; ++ni) {
                int dd = jg0 - ig[ni];  // diagonal at r == -dd
                float sb = si[ni] + EPSF;
#pragma unroll
                for (int r = 0; r < 4; ++r) {
                    float d2 = fmaxf(fmaf(-2.0f, acc[mi][ni][r], sb + sjp[r]), 1e-12f);
                    float x = -SCALEF * fast_sqrtf(d2);
                    float e = __expf(x - Ri4[ni]);
                    bool ii = (cjp[r] == ci4[ni]);
                    bool dg = ((dd + r) == 0);
                    bool okI = ii && !dg;
                    sIa[ni] += okI ? e : 0.0f;
                    sXa[ni] += ii ? 0.0f : e;
                    bubble_insert<LI>(tI[ni], okI ? x : -INFINITY);
                    bubble_insert<LX>(tX[ni], ii ? -INFINITY : x);
                }
            }
        }
    }

    // merge across the 4 quads sharing each row (butterfly, offsets 16 & 32).
    // Snapshot ALL partner values BEFORE mutating own lists (lockstep hazard).
#pragma unroll
    for (int off = 16; off <= 32; off <<= 1) {
#pragma unroll
        for (int ni = 0; ni < 4; ++ni) {
            sIa[ni] += __shfl_xor(sIa[ni], off, 64);
            sXa[ni] += __shfl_xor(sXa[ni], off, 64);
            float oI[LI], oX[LX];
#pragma unroll
            for (int q = 0; q < LI; ++q) oI[q] = __shfl_xor(tI[ni][q], off, 64);
#pragma unroll
            for (int q = 0; q < LX; ++q) oX[q] = __shfl_xor(tX[ni][q], off, 64);
#pragma unroll
            for (int q = 0; q < LI; ++q) bubble_insert<LI>(tI[ni], oI[q]);
#pragma unroll
            for (int q = 0; q < LX; ++q) bubble_insert<LX>(tX[ni], oX[q]);
        }
    }

    if (quad == 0) {
        int p = cid * 2 + wr;
#pragma unroll
        for (int ni = 0; ni < 4; ++ni) {
            size_t idx = (size_t)p * N + ig[ni];
            partA[idx] = make_float4(tI[ni][0], tI[ni][1], tI[ni][2], sIa[ni]);
            partB[idx] = make_float4(tX[ni][0], tX[ni][1], tX[ni][2], tX[ni][3]);
            partC[idx] = make_float4(tX[ni][4], tX[ni][5], sXa[ni], 0.0f);
        }
    }
}

// ---------------- Kernel 3: merge partials -> loss (atomic accumulate) --------
__global__ __launch_bounds__(256) void merge_kernel(const float4* __restrict__ partA,
                                                    const float4* __restrict__ partB,
                                                    const float4* __restrict__ partC,
                                                    const float* __restrict__ Rrow,
                                                    float* __restrict__ out) {
    __shared__ float sbuf[256];
    int tid = threadIdx.x;
    int row = blockIdx.x * 256 + tid;
    float mI[LI] = {-INFINITY, -INFINITY, -INFINITY};
    float mX[LX] = {-INFINITY, -INFINITY, -INFINITY, -INFINITY, -INFINITY, -INFINITY};
    float SI = 0.0f, SX = 0.0f;
#pragma unroll 1
    for (int p = 0; p < PPARTS; ++p) {
        size_t idx = (size_t)p * N + row;
        float4 a = partA[idx];
        float4 b = partB[idx];
        float4 c = partC[idx];
        bubble_insert<LI>(mI, a.x); bubble_insert<LI>(mI, a.y); bubble_insert<LI>(mI, a.z);
        SI += a.w;
        bubble_insert<LX>(mX, b.x); bubble_insert<LX>(mX, b.y);
        bubble_insert<LX>(mX, b.z); bubble_insert<LX>(mX, b.w);
        bubble_insert<LX>(mX, c.x); bubble_insert<LX>(mX, c.y);
        SX += c.z;
    }
    float R = Rrow[row];
    // intra: exclude diag (by construction) + top-3 values
    float subI = __expf(mI[0] - R) + __expf(mI[1] - R) + __expf(mI[2] - R);
    float restI = fmaxf(SI - subI, 1e-37f);
    float yI = R + logf(restI);
    float hI = fmaxf(yI + SCALEF * sqrtf(EPSF) + MARGIN_INTRA, 0.0f);  // -x0 = +10*sqrt(eps)
    // inter: exclude top-6 values
    float subX = __expf(mX[0] - R) + __expf(mX[1] - R) + __expf(mX[2] - R) +
                 __expf(mX[3] - R) + __expf(mX[4] - R) + __expf(mX[5] - R);
    float restX = fmaxf(SX - subX, 1e-37f);
    float yX = R + logf(restX);
    float hX = fmaxf(-mX[0] + yX + MARGIN_INTER, 0.0f);
    sbuf[tid] = hI + 0.5f * hX;
    __syncthreads();
    for (int stride = 128; stride > 0; stride >>= 1) {
        if (tid < stride) sbuf[tid] += sbuf[tid + stride];
        __syncthreads();
    }
    if (tid == 0) atomicAdd(out, sbuf[0] * (1.0f / (float)N));
}

extern "C" void kernel_launch(void* const* d_in, const int* in_sizes, int n_in,
                              void* d_out, int out_size, void* d_ws, size_t ws_size,
                              hipStream_t stream) {
    const float* F = (const float*)d_in[0];
    const int* camid = (const int*)d_in[1];
    float* out = (float*)d_out;
    char* ws = (char*)d_ws;

    ushort_t* Fhi = (ushort_t*)ws;                               // 2 MB
    ushort_t* Flo = Fhi + (size_t)N * D;                         // 2 MB
    float* sq = (float*)(ws + 2 * (size_t)N * D * 2);            // 16 KB
    float* Rrow = sq + N;                                        // 16 KB
    int* perm = (int*)(Rrow + N);                                // 16 KB
    int* camid_s = perm + N;                                     // 16 KB
    float4* partA = (float4*)(ws + 2 * (size_t)N * D * 2 + 4 * N * 4);  // 4 MB each
    float4* partB = partA + (size_t)PPARTS * N;
    float4* partC = partB + (size_t)PPARTS * N;

    perm_kernel<<<1, 512, 0, stream>>>(camid, perm, camid_s, out);
    prep_kernel<<<N, 64, 0, stream>>>(F, perm, Fhi, Flo, sq, Rrow);
    fused_kernel<<<dim3(NJB, NIB), 256, 0, stream>>>(Fhi, Flo, sq, Rrow, camid_s,
                                                     partA, partB, partC);
    merge_kernel<<<N / 256, 256, 0, stream>>>(partA, partB, partC, Rrow, out);
}